// Round 17
// baseline (796.417 us; speedup 1.0000x reference)
//
#include <hip/hip_runtime.h>
#include <math.h>

typedef float f32x2 __attribute__((ext_vector_type(2)));
static __device__ __forceinline__ f32x2 f2(float a, float b) { f32x2 r; r.x = a; r.y = b; return r; }

#define ALPHA 0.5f
#define BETA  2.0e-4f   // 0.02 * 0.1 * 0.1
#define DELTA 0.1f
#define N_ITER 10

#define DD 192
#define HH 192
#define WW 192
#define HWW (192*192)
#define CHE 16         // err kernel: y-rows per block
#define CHU 8          // upd kernel: y-rows per block (8 -> 6912 waves)
#define XT  64         // upd kernel: x-tile width (one wave)
#define NSMAX 4        // err slices touching a z-pair window (stride>=2 -> <=3)

// ---------------------------------------------------------------------------
// K1: err_xy[s] = conv_x(conv_y( A(x)[s] - slices[s], wy_flip ), wx_flip)
// (unchanged from round 7 — passing)
// ---------------------------------------------------------------------------
__global__ __launch_bounds__(192) void srr_err_k(
    const float* __restrict__ x, const float* __restrict__ slices,
    const float* __restrict__ psf, const int* __restrict__ stride_p,
    float* __restrict__ err_xy, int n_slices)
{
    __shared__ float spsf[125];
    __shared__ float wsum[16];
    __shared__ float wzs[5], wys[5], wxs[5];
    __shared__ float raw[5][2][200];   // raw x rows [plane][slot][2+x], halos 0
    __shared__ float erw[2][200];      // err rows [slot][2+x], halos 0

    const int t = threadIdx.x;
    if (t < 125) spsf[t] = psf[t];
    if (t >= 128 && t < 176) {         // zero halo cols: 10 raw rows + 2 erw rows
        int q = t - 128, row = q >> 2, p = q & 3;
        int col = (p < 2) ? p : (192 + p);
        if (row < 10) raw[row >> 1][row & 1][col] = 0.f;
        else          erw[row - 10][col] = 0.f;
    }
    __syncthreads();
    if (t < 5)               { float s=0; for (int k=0;k<25;++k) s+=spsf[t*25+k]; wsum[t]=s; }
    else if (t>=8 && t<13)   { int b=t-8;  float s=0; for(int a=0;a<5;++a) for(int c=0;c<5;++c) s+=spsf[a*25+b*5+c]; wsum[t-3]=s; }
    else if (t>=16 && t<21)  { int c=t-16; float s=0; for(int a=0;a<5;++a) for(int b=0;b<5;++b) s+=spsf[a*25+b*5+c]; wsum[t-6]=s; }
    __syncthreads();
    if (t == 0) {
        float T = wsum[0]+wsum[1]+wsum[2]+wsum[3]+wsum[4];
        float iT = 1.0f / T;
        for (int a=0;a<5;++a) wzs[a] = wsum[a]   * iT;
        for (int b=0;b<5;++b) wys[b] = wsum[5+b] * iT;
        for (int c=0;c<5;++c) wxs[c] = wsum[10+c];
    }
    __syncthreads();

    // XCD-aware swizzle: grid (HH/CHE, n_slices), y-chunk fastest.
    const unsigned nwg  = gridDim.x * gridDim.y;
    const unsigned chk  = nwg >> 3;                    // nwg % 8 == 0
    const unsigned flat = blockIdx.x + gridDim.x * blockIdx.y;
    const unsigned nid  = (flat & 7u) * chk + (flat >> 3);
    const int y0 = (int)(nid % gridDim.x) * CHE;
    const int s  = (int)(nid / gridDim.x);
    const int stride = *stride_p;
    const int z = s * stride;

    float wzr[5], wyr[5], wxr[5], wyf[5], wxf[5];
    #pragma unroll
    for (int i = 0; i < 5; ++i) {
        wzr[i]=wzs[i]; wyr[i]=wys[i]; wxr[i]=wxs[i];
        wyf[i]=wys[4-i]; wxf[i]=wxs[4-i];          // flipped for the adjoint
    }

    const float* xp[5]; bool okp[5];
    #pragma unroll
    for (int a = 0; a < 5; ++a) {
        int zz = z + a - 2;
        okp[a] = (zz >= 0) && (zz < DD);
        xp[a] = x + (size_t)(okp[a] ? zz : 0) * HWW + (ptrdiff_t)(y0 - 4) * WW + t;
    }
    const float* spm = slices + (size_t)s * HWW + (ptrdiff_t)(y0 - 2) * WW + t;
    float*       epo = err_xy + (size_t)s * HWW + (size_t)y0 * WW + t;

    float xv[5];
    {
        bool yg = (y0 - 4 >= 0);
        #pragma unroll
        for (int a = 0; a < 5; ++a) { xv[a] = (okp[a] && yg) ? *xp[a] : 0.f; xp[a] += WW; }
    }
    float P[5] = {0.f,0.f,0.f,0.f,0.f};
    float Q[5] = {0.f,0.f,0.f,0.f,0.f};
    float er_prev = 0.f, sv = 0.f, svn = 0.f;

    for (int k = 0; k < CHE + 9; ++k) {
        const int yy = y0 - 4 + k;
        const int sl = k & 1;
        #pragma unroll
        for (int a = 0; a < 5; ++a) raw[a][sl][2 + t] = xv[a];
        erw[sl][2 + t] = er_prev;                  // err row (yy-3)
        __syncthreads();
        {   // prefetch x rows (yy+1) + slices row (yy-1); overlaps compute
            int yn = yy + 1;
            bool yg = (yn >= 0) && (yn < HH);
            #pragma unroll
            for (int a = 0; a < 5; ++a) { xv[a] = (okp[a] && yg) ? *xp[a] : 0.f; xp[a] += WW; }
            int yv = yy - 1;
            if (yv >= y0 - 2 && yv < y0 + CHE + 2) {
                svn = (yv >= 0 && yv < HH) ? *spm : 0.f;
                spm += WW;
            } else svn = 0.f;
        }
        // forward: A(x) row yy
        float cxz = 0.f;
        #pragma unroll
        for (int a = 0; a < 5; ++a) {
            float c4 = 0.f;
            #pragma unroll
            for (int c = 0; c < 5; ++c) c4 = fmaf(wxr[c], raw[a][sl][t + c], c4);
            cxz = fmaf(wzr[a], c4, cxz);
        }
        P[0]=fmaf(wyr[4],cxz,P[0]); P[1]=fmaf(wyr[3],cxz,P[1]); P[2]=fmaf(wyr[2],cxz,P[2]);
        P[3]=fmaf(wyr[1],cxz,P[3]); P[4]=fmaf(wyr[0],cxz,P[4]);
        {   // finalize err row (yy-2), staged next step
            int yr = yy - 2;
            er_prev = (yr >= 0 && yr < HH) ? (P[0] - sv) : 0.f;
        }
        sv = svn;
        // adjoint xy: x-conv staged err row (yy-3), flipped weights
        float ex = 0.f;
        #pragma unroll
        for (int c = 0; c < 5; ++c) ex = fmaf(wxf[c], erw[sl][t + c], ex);
        Q[0]=fmaf(wyf[4],ex,Q[0]); Q[1]=fmaf(wyf[3],ex,Q[1]); Q[2]=fmaf(wyf[2],ex,Q[2]);
        Q[3]=fmaf(wyf[1],ex,Q[3]); Q[4]=fmaf(wyf[0],ex,Q[4]);
        {   // store err_xy row (yy-5)
            int yq = yy - 5;
            if (yq >= y0) { *epo = Q[0]; epo += WW; }
        }
        P[0]=P[1]; P[1]=P[2]; P[2]=P[3]; P[3]=P[4]; P[4]=0.f;
        Q[0]=Q[1]; Q[1]=Q[2]; Q[2]=Q[3]; Q[3]=Q[4]; Q[4]=0.f;
    }
}

// ---------------------------------------------------------------------------
// K2: x_out = x - ALPHA*( At_z(err_xy) + BETA*dR(x) ), optional final relu.
// Round-16 structure; HYBRID rsqrt: the 12 W2-class terms use HW v_rsq
// (trans pipe, exact), the W1/W3 terms use packed magic+Newton (VALU pipe)
// — balances the two execution pipes instead of saturating one.
// ---------------------------------------------------------------------------
__global__ __launch_bounds__(256, 4) void srr_upd_k(
    const float* __restrict__ x, const float* __restrict__ err_xy,
    const float* __restrict__ psf, const int* __restrict__ stride_p,
    float* __restrict__ xout, int n_slices, int apply_relu)
{
    __shared__ float spsf[125];
    __shared__ float wsum[8];
    __shared__ f32x2 xr2[4][4][68][2];         // [wave][row-slot][col][{(x0,x1),(x2,x3)}]
    __shared__ int   s_cnt[4];
    __shared__ int   s_sidx[4][NSMAX];
    __shared__ float s_w0[4][NSMAX], s_w1[4][NSMAX];

    const int t = threadIdx.x;                 // lane 0..63
    const int w = threadIdx.y;                 // wave 0..3
    const int ft = t + 64 * w;
    if (ft < 125) spsf[ft] = psf[ft];
    __syncthreads();
    if (ft < 5) { float s=0; for (int k=0;k<25;++k) s+=spsf[ft*25+k]; wsum[ft]=s; }
    __syncthreads();

    // XCD-aware swizzle: grid (HH/CHU, WW/XT, DD/8), y-chunk fastest.
    const unsigned nwg  = gridDim.x * gridDim.y * gridDim.z;
    const unsigned chk  = nwg >> 3;                    // nwg % 8 == 0
    const unsigned flat = blockIdx.x + gridDim.x * (blockIdx.y + gridDim.y * blockIdx.z);
    const unsigned nid  = (flat & 7u) * chk + (flat >> 3);
    const int ych = (int)(nid % gridDim.x);
    const unsigned q2 = nid / gridDim.x;
    const int xt  = (int)(q2 % gridDim.y);
    const int zq  = (int)(q2 / gridDim.y);
    // wave-uniform by construction; readfirstlane makes it provably scalar
    const int z0  = __builtin_amdgcn_readfirstlane(8 * zq + 2 * w);

    if (t == 0) {                              // lane 0 of each wave
        float T = wsum[0]+wsum[1]+wsum[2]+wsum[3]+wsum[4];
        float iT = 1.0f / T;
        float wzf[5];
        for (int a=0;a<5;++a) wzf[a] = wsum[4-a] * iT;   // flipped z weights
        int stride = *stride_p;
        int cnt = 0;
        for (int d = -2; d <= 3; ++d) {        // err planes z0-2 .. z0+3
            int zz = z0 + d;
            if (zz >= 0 && zz < DD && (zz % stride) == 0) {
                int ss = zz / stride;
                if (ss < n_slices && cnt < NSMAX) {
                    s_sidx[w][cnt] = ss;
                    s_w0[w][cnt] = (d <= 2)  ? wzf[d + 2] : 0.f;   // weight for z0
                    s_w1[w][cnt] = (d >= -1) ? wzf[d + 1] : 0.f;   // weight for z0+1
                    ++cnt;
                }
            }
        }
        s_cnt[w] = cnt;
    }
    __syncthreads();                           // publish per-wave init

    const int x0  = xt * XT;
    const int y0  = ych * CHU;
    const int cnt = __builtin_amdgcn_readfirstlane(s_cnt[w]);
    const int gx  = x0 + t;

    f32x2 w01r[NSMAX];                         // packed data-term z-weights
    const float* ebase[NSMAX];                 // SGPR slice bases
    #pragma unroll
    for (int j = 0; j < NSMAX; ++j) {
        bool v = (j < cnt);
        w01r[j] = f2(v ? s_w0[w][j] : 0.f, v ? s_w1[w][j] : 0.f);
        int sj = __builtin_amdgcn_readfirstlane(v ? s_sidx[w][j] : 0);
        ebase[j] = err_xy + (size_t)sj * HWW;
    }
    const float* xbase[4]; bool okp[4];        // SGPR plane bases (scalar z0)
    #pragma unroll
    for (int zo = 0; zo < 4; ++zo) {
        int zz = z0 - 1 + zo;
        okp[zo] = (zz >= 0) && (zz < DD);
        xbase[zo] = x + (size_t)(okp[zo] ? zz : 0) * HWW;
    }
    // halo columns (+-1 only): lane 0 -> local col 1 (gx=x0-1),
    //                          lane 1 -> local col 66 (gx=x0+64)
    const int  hloc = (t == 0) ? 1 : 66;
    const int  hgx  = (t == 0) ? (x0 - 1) : (x0 + 64);
    const bool hol  = (t < 2) && (hgx >= 0) && (hgx < WW);
    const int  hgxc = (hgx < 0) ? 0 : ((hgx > WW - 1) ? (WW - 1) : hgx);
    float* const ob0 = xout + (size_t)z0 * HWW;
    float* const ob1 = xout + (size_t)(z0 + 1) * HWW;
    const bool okz0 = (z0 >= 1);
    const bool okz1 = (z0 + 1 <= DD - 2);
    const bool tok  = (gx >= 1) && (gx <= WW - 2);

    // shared 32-bit row offsets (one v_add each per step)
    int voff  = (y0 - 2) * WW + gx;            // x-row stream (guarded when OOB)
    int hvoff = (y0 - 2) * WW + hgxc;          // halo stream
    int evoff = y0 * WW + gx;                  // err_xy stream
    int ovoff = y0 * WW + gx;                  // output stream

    // 2-deep prefetch queues: A = row to stage this step, B = row after.
    float xvA[4], xvB[4], hxA[4], hxB[4];
    {
        bool ygA = (y0 - 2 >= 0);
        #pragma unroll
        for (int zo = 0; zo < 4; ++zo) {
            xvA[zo] = (okp[zo] && ygA)        ? xbase[zo][voff]  : 0.f;
            hxA[zo] = (hol && okp[zo] && ygA) ? xbase[zo][hvoff] : 0.f;
        }
        voff += WW; hvoff += WW;
        bool ygB = (y0 - 1 >= 0);
        #pragma unroll
        for (int zo = 0; zo < 4; ++zo) {
            xvB[zo] = (okp[zo] && ygB)        ? xbase[zo][voff]  : 0.f;
            hxB[zo] = (hol && okp[zo] && ygB) ? xbase[zo][hvoff] : 0.f;
        }
        voff += WW; hvoff += WW;
    }
    float ev[NSMAX] = {0.f,0.f,0.f,0.f}, evn[NSMAX] = {0.f,0.f,0.f,0.f};
    f32x2 rr2 = f2(0.f, 0.f);
    // 3-row delay line of own-column plane pairs: d0=row yy-2, d1=yy-1, d2=yy
    f32x2 d0[3], d1[3], d2[3];
    #pragma unroll
    for (int q = 0; q < 3; ++q) { d0[q]=f2(0.f,0.f); d1[q]=f2(0.f,0.f); d2[q]=f2(0.f,0.f); }

    const float W1 = 1.0f / (1.0f * DELTA * DELTA);
    const float W2 = 1.0f / (2.0f * DELTA * DELTA);
    const float W3 = 1.0f / (3.0f * DELTA * DELTA);
    const f32x2 one2 = f2(1.0f, 1.0f);
    const f32x2 nh2  = f2(-0.5f, -0.5f);
    const f32x2 th2  = f2(1.5f, 1.5f);

    for (int k = 0; k < CHU + 4; ++k) {
        const int yy  = y0 - 2 + k;
        const int sl4 = k & 3;
        // build row-yy pairs; stage outer pairs to LDS (16B contiguous)
        f32x2 nd0 = f2(xvA[0], xvA[1]);
        f32x2 nd1 = f2(xvA[1], xvA[2]);
        f32x2 nd3 = f2(xvA[2], xvA[3]);
        xr2[w][sl4][2 + t][0] = nd0;
        xr2[w][sl4][2 + t][1] = nd3;
        if (t < 2) {
            xr2[w][sl4][hloc][0] = f2(hxA[0], hxA[1]);
            xr2[w][sl4][hloc][1] = f2(hxA[2], hxA[3]);
        }
        #pragma unroll
        for (int q = 0; q < 3; ++q) { d0[q] = d1[q]; d1[q] = d2[q]; }
        d2[0] = nd0; d2[1] = nd1; d2[2] = nd3;
        // single wave per z-pair: no barrier; DS ordering is program-order
        {   // rotate queue; issue loads for row yy+2 (consumed 2 steps later)
            #pragma unroll
            for (int zo = 0; zo < 4; ++zo) { xvA[zo] = xvB[zo]; hxA[zo] = hxB[zo]; }
            int yn = yy + 2;            // = y0 + k >= 0 always
            bool yg = (yn < HH);
            #pragma unroll
            for (int zo = 0; zo < 4; ++zo) {
                xvB[zo] = (okp[zo] && yg)        ? xbase[zo][voff]  : 0.f;
                hxB[zo] = (hol && okp[zo] && yg) ? xbase[zo][hvoff] : 0.f;
            }
            voff += WW; hvoff += WW;
            int r = yy - 1;
            if (r >= y0 && r < y0 + CHU) {
                #pragma unroll
                for (int j = 0; j < NSMAX; ++j) {
                    if (j < cnt) evn[j] = ebase[j][evoff];
                }
                evoff += WW;
            }
        }
        // store y_s = yy-2 (uses ev + rr2 from previous step; center = d0[1])
        if (yy - 2 >= y0) {
            f32x2 c2 = d0[1];
            f32x2 g2 = f2(0.f, 0.f);
            #pragma unroll
            for (int j = 0; j < NSMAX; ++j) {
                f32x2 e = f2(ev[j], ev[j]);
                g2 = w01r[j] * e + g2;
            }
            f32x2 o2 = c2 - f2(ALPHA, ALPHA) * (g2 + f2(BETA, BETA) * rr2);
            float o0 = o2.x, o1 = o2.y;
            if (apply_relu) { o0 = fmaxf(o0, 0.f); o1 = fmaxf(o1, 0.f); }
            ob0[ovoff] = o0;
            ob1[ovoff] = o1;
            ovoff += WW;
        }
        #pragma unroll
        for (int j = 0; j < NSMAX; ++j) ev[j] = evn[j];
        // packed regularizer for y_r = yy-1 (consumed next step)
        const int yr = yy - 1;
        if (yr >= y0 && yr < y0 + CHU) {
            const bool oky = (yr >= 1) && (yr <= HH - 2);
            const int rs[3] = { (k + 2) & 3, (k + 3) & 3, k & 3 };  // yr-1, yr, yr+1
            const f32x2 v02 = d1[1];
            f32x2 acc = f2(0.f, 0.f), accb = f2(0.f, 0.f);
            #pragma unroll
            for (int ri = 0; ri < 3; ++ri) {
                // neighbor columns: one 16B read per side, middle pair rebuilt
                f32x2 nbv[3][3];
                {
                    f32x2 pa = xr2[w][rs[ri]][1 + t][0];
                    f32x2 pb = xr2[w][rs[ri]][1 + t][1];
                    nbv[0][0] = pa; nbv[0][1] = f2(pa.y, pb.x); nbv[0][2] = pb;
                }
                {
                    f32x2 pa = xr2[w][rs[ri]][3 + t][0];
                    f32x2 pb = xr2[w][rs[ri]][3 + t][1];
                    nbv[2][0] = pa; nbv[2][1] = f2(pa.y, pb.x); nbv[2][2] = pb;
                }
                nbv[1][0] = (ri == 0) ? d0[0] : ((ri == 1) ? d1[0] : d2[0]);
                nbv[1][1] = (ri == 0) ? d0[1] : ((ri == 1) ? d1[1] : d2[1]);
                nbv[1][2] = (ri == 0) ? d0[2] : ((ri == 1) ? d1[2] : d2[2]);
                #pragma unroll
                for (int ci = 0; ci < 3; ++ci) {
                    #pragma unroll
                    for (int q = 0; q < 3; ++q) {
                        if (ri == 1 && ci == 1 && q == 1) continue;
                        const int sidx = (q != 1) + (ri != 1) + (ci != 1);
                        const float Wc = (sidx == 1) ? W1 : ((sidx == 2) ? W2 : W3);
                        f32x2 nb = nbv[ci][q];
                        f32x2 dv = v02 - nb;                      // pk_add
                        f32x2 dw = dv * f2(Wc, Wc);               // pk_mul
                        f32x2 a  = dv * dw + one2;                // pk_fma  (a >= 1)
                        f32x2 r2;
                        if (sidx == 2) {
                            // trans pipe: exact HW rsqrt (runs parallel to VALU)
                            r2 = f2(rsqrtf(a.x), rsqrtf(a.y));
                        } else {
                            // VALU pipe: packed magic rsqrt + 1 Newton
                            r2 = f2(
                                __uint_as_float(0x5f3759dfu - (__float_as_uint(a.x) >> 1)),
                                __uint_as_float(0x5f3759dfu - (__float_as_uint(a.y) >> 1)));
                            f32x2 ah = a * nh2;                   // pk_mul (-0.5a)
                            f32x2 tt = r2 * r2;                   // pk_mul
                            tt = ah * tt + th2;                   // pk_fma (1.5-0.5ar^2)
                            r2 = r2 * tt;                         // pk_mul
                        }
                        if ((ri + ci + q) & 1) accb = dw * r2 + accb;
                        else                   acc  = dw * r2 + acc;
                    }
                }
            }
            f32x2 sum = acc + accb;
            rr2.x = (okz0 && oky && tok) ? sum.x : 0.f;
            rr2.y = (okz1 && oky && tok) ? sum.y : 0.f;
        } else { rr2 = f2(0.f, 0.f); }
    }
}

extern "C" void kernel_launch(void* const* d_in, const int* in_sizes, int n_in,
                              void* d_out, int out_size, void* d_ws, size_t ws_size,
                              hipStream_t stream) {
    // inputs: 0=theta (unused), 1=slices, 2=volume, 3=psf, 4=stride
    const float* slices = (const float*)d_in[1];
    const float* volume = (const float*)d_in[2];
    const float* psf    = (const float*)d_in[3];
    const int*   strd   = (const int*)d_in[4];

    const int n_slices = in_sizes[1] / (HH * WW);   // 96

    float* x_ws   = (float*)d_ws;                   // 192^3 floats
    float* err_xy = x_ws + (size_t)DD * HH * WW;    // n_slices*H*W floats
    float* x_out  = (float*)d_out;                  // pong buffer / final output

    dim3 blkE(192, 1, 1);
    dim3 gA(HH / CHE, n_slices);            // (12, 96): y-chunk fastest
    dim3 blkU(XT, 4, 1);                    // 4 waves/block, one z-pair each
    dim3 gB(HH / CHU, WW / XT, DD / 8);     // (24, 3, 24): y-chunk fastest

    const float* src = volume;
    for (int it = 0; it < N_ITER; ++it) {
        float* dst = (it & 1) ? x_out : x_ws;
        srr_err_k<<<gA, blkE, 0, stream>>>(src, slices, psf, strd, err_xy, n_slices);
        srr_upd_k<<<gB, blkU, 0, stream>>>(src, err_xy, psf, strd, dst, n_slices,
                                           (it == N_ITER - 1) ? 1 : 0);
        src = dst;
    }
}

// Round 18
// 715.122 us; speedup vs baseline: 1.1137x; 1.1137x over previous
//
#include <hip/hip_runtime.h>
#include <math.h>

typedef float f32x2 __attribute__((ext_vector_type(2)));
static __device__ __forceinline__ f32x2 f2(float a, float b) { f32x2 r; r.x = a; r.y = b; return r; }

#define ALPHA 0.5f
#define BETA  2.0e-4f   // 0.02 * 0.1 * 0.1
#define DELTA 0.1f
#define N_ITER 10

#define DD 192
#define HH 192
#define WW 192
#define HWW (192*192)
#define CHE 16         // err kernel: y-rows per block
#define CHU 8          // upd kernel: y-rows per block (8 -> 6912 waves)
#define XT  64         // upd kernel: x-tile width (one wave)
#define NSMAX 4        // err slices touching a z-pair window (stride>=2 -> <=3)

// ---------------------------------------------------------------------------
// K1: err_xy[s] = conv_x(conv_y( A(x)[s] - slices[s], wy_flip ), wx_flip)
// (unchanged from round 7 — passing)
// ---------------------------------------------------------------------------
__global__ __launch_bounds__(192) void srr_err_k(
    const float* __restrict__ x, const float* __restrict__ slices,
    const float* __restrict__ psf, const int* __restrict__ stride_p,
    float* __restrict__ err_xy, int n_slices)
{
    __shared__ float spsf[125];
    __shared__ float wsum[16];
    __shared__ float wzs[5], wys[5], wxs[5];
    __shared__ float raw[5][2][200];   // raw x rows [plane][slot][2+x], halos 0
    __shared__ float erw[2][200];      // err rows [slot][2+x], halos 0

    const int t = threadIdx.x;
    if (t < 125) spsf[t] = psf[t];
    if (t >= 128 && t < 176) {         // zero halo cols: 10 raw rows + 2 erw rows
        int q = t - 128, row = q >> 2, p = q & 3;
        int col = (p < 2) ? p : (192 + p);
        if (row < 10) raw[row >> 1][row & 1][col] = 0.f;
        else          erw[row - 10][col] = 0.f;
    }
    __syncthreads();
    if (t < 5)               { float s=0; for (int k=0;k<25;++k) s+=spsf[t*25+k]; wsum[t]=s; }
    else if (t>=8 && t<13)   { int b=t-8;  float s=0; for(int a=0;a<5;++a) for(int c=0;c<5;++c) s+=spsf[a*25+b*5+c]; wsum[t-3]=s; }
    else if (t>=16 && t<21)  { int c=t-16; float s=0; for(int a=0;a<5;++a) for(int b=0;b<5;++b) s+=spsf[a*25+b*5+c]; wsum[t-6]=s; }
    __syncthreads();
    if (t == 0) {
        float T = wsum[0]+wsum[1]+wsum[2]+wsum[3]+wsum[4];
        float iT = 1.0f / T;
        for (int a=0;a<5;++a) wzs[a] = wsum[a]   * iT;
        for (int b=0;b<5;++b) wys[b] = wsum[5+b] * iT;
        for (int c=0;c<5;++c) wxs[c] = wsum[10+c];
    }
    __syncthreads();

    // XCD-aware swizzle: grid (HH/CHE, n_slices), y-chunk fastest.
    const unsigned nwg  = gridDim.x * gridDim.y;
    const unsigned chk  = nwg >> 3;                    // nwg % 8 == 0
    const unsigned flat = blockIdx.x + gridDim.x * blockIdx.y;
    const unsigned nid  = (flat & 7u) * chk + (flat >> 3);
    const int y0 = (int)(nid % gridDim.x) * CHE;
    const int s  = (int)(nid / gridDim.x);
    const int stride = *stride_p;
    const int z = s * stride;

    float wzr[5], wyr[5], wxr[5], wyf[5], wxf[5];
    #pragma unroll
    for (int i = 0; i < 5; ++i) {
        wzr[i]=wzs[i]; wyr[i]=wys[i]; wxr[i]=wxs[i];
        wyf[i]=wys[4-i]; wxf[i]=wxs[4-i];          // flipped for the adjoint
    }

    const float* xp[5]; bool okp[5];
    #pragma unroll
    for (int a = 0; a < 5; ++a) {
        int zz = z + a - 2;
        okp[a] = (zz >= 0) && (zz < DD);
        xp[a] = x + (size_t)(okp[a] ? zz : 0) * HWW + (ptrdiff_t)(y0 - 4) * WW + t;
    }
    const float* spm = slices + (size_t)s * HWW + (ptrdiff_t)(y0 - 2) * WW + t;
    float*       epo = err_xy + (size_t)s * HWW + (size_t)y0 * WW + t;

    float xv[5];
    {
        bool yg = (y0 - 4 >= 0);
        #pragma unroll
        for (int a = 0; a < 5; ++a) { xv[a] = (okp[a] && yg) ? *xp[a] : 0.f; xp[a] += WW; }
    }
    float P[5] = {0.f,0.f,0.f,0.f,0.f};
    float Q[5] = {0.f,0.f,0.f,0.f,0.f};
    float er_prev = 0.f, sv = 0.f, svn = 0.f;

    for (int k = 0; k < CHE + 9; ++k) {
        const int yy = y0 - 4 + k;
        const int sl = k & 1;
        #pragma unroll
        for (int a = 0; a < 5; ++a) raw[a][sl][2 + t] = xv[a];
        erw[sl][2 + t] = er_prev;                  // err row (yy-3)
        __syncthreads();
        {   // prefetch x rows (yy+1) + slices row (yy-1); overlaps compute
            int yn = yy + 1;
            bool yg = (yn >= 0) && (yn < HH);
            #pragma unroll
            for (int a = 0; a < 5; ++a) { xv[a] = (okp[a] && yg) ? *xp[a] : 0.f; xp[a] += WW; }
            int yv = yy - 1;
            if (yv >= y0 - 2 && yv < y0 + CHE + 2) {
                svn = (yv >= 0 && yv < HH) ? *spm : 0.f;
                spm += WW;
            } else svn = 0.f;
        }
        // forward: A(x) row yy
        float cxz = 0.f;
        #pragma unroll
        for (int a = 0; a < 5; ++a) {
            float c4 = 0.f;
            #pragma unroll
            for (int c = 0; c < 5; ++c) c4 = fmaf(wxr[c], raw[a][sl][t + c], c4);
            cxz = fmaf(wzr[a], c4, cxz);
        }
        P[0]=fmaf(wyr[4],cxz,P[0]); P[1]=fmaf(wyr[3],cxz,P[1]); P[2]=fmaf(wyr[2],cxz,P[2]);
        P[3]=fmaf(wyr[1],cxz,P[3]); P[4]=fmaf(wyr[0],cxz,P[4]);
        {   // finalize err row (yy-2), staged next step
            int yr = yy - 2;
            er_prev = (yr >= 0 && yr < HH) ? (P[0] - sv) : 0.f;
        }
        sv = svn;
        // adjoint xy: x-conv staged err row (yy-3), flipped weights
        float ex = 0.f;
        #pragma unroll
        for (int c = 0; c < 5; ++c) ex = fmaf(wxf[c], erw[sl][t + c], ex);
        Q[0]=fmaf(wyf[4],ex,Q[0]); Q[1]=fmaf(wyf[3],ex,Q[1]); Q[2]=fmaf(wyf[2],ex,Q[2]);
        Q[3]=fmaf(wyf[1],ex,Q[3]); Q[4]=fmaf(wyf[0],ex,Q[4]);
        {   // store err_xy row (yy-5)
            int yq = yy - 5;
            if (yq >= y0) { *epo = Q[0]; epo += WW; }
        }
        P[0]=P[1]; P[1]=P[2]; P[2]=P[3]; P[3]=P[4]; P[4]=0.f;
        Q[0]=Q[1]; Q[1]=Q[2]; Q[2]=Q[3]; Q[3]=Q[4]; Q[4]=0.f;
    }
}

// ---------------------------------------------------------------------------
// K2: x_out = x - ALPHA*( At_z(err_xy) + BETA*dR(x) ), optional final relu.
// Round-16 structure (all-magic packed rsqrt — best measured config); the 8
// W3 corner terms (sidx==3, smallest magnitude) use the magic SEED ONLY
// (no Newton): saves 32 pk-ops/step, error contribution ~1e-3 over 10 iters.
// ---------------------------------------------------------------------------
__global__ __launch_bounds__(256, 4) void srr_upd_k(
    const float* __restrict__ x, const float* __restrict__ err_xy,
    const float* __restrict__ psf, const int* __restrict__ stride_p,
    float* __restrict__ xout, int n_slices, int apply_relu)
{
    __shared__ float spsf[125];
    __shared__ float wsum[8];
    __shared__ f32x2 xr2[4][4][68][2];         // [wave][row-slot][col][{(x0,x1),(x2,x3)}]
    __shared__ int   s_cnt[4];
    __shared__ int   s_sidx[4][NSMAX];
    __shared__ float s_w0[4][NSMAX], s_w1[4][NSMAX];

    const int t = threadIdx.x;                 // lane 0..63
    const int w = threadIdx.y;                 // wave 0..3
    const int ft = t + 64 * w;
    if (ft < 125) spsf[ft] = psf[ft];
    __syncthreads();
    if (ft < 5) { float s=0; for (int k=0;k<25;++k) s+=spsf[ft*25+k]; wsum[ft]=s; }
    __syncthreads();

    // XCD-aware swizzle: grid (HH/CHU, WW/XT, DD/8), y-chunk fastest.
    const unsigned nwg  = gridDim.x * gridDim.y * gridDim.z;
    const unsigned chk  = nwg >> 3;                    // nwg % 8 == 0
    const unsigned flat = blockIdx.x + gridDim.x * (blockIdx.y + gridDim.y * blockIdx.z);
    const unsigned nid  = (flat & 7u) * chk + (flat >> 3);
    const int ych = (int)(nid % gridDim.x);
    const unsigned q2 = nid / gridDim.x;
    const int xt  = (int)(q2 % gridDim.y);
    const int zq  = (int)(q2 / gridDim.y);
    // wave-uniform by construction; readfirstlane makes it provably scalar
    const int z0  = __builtin_amdgcn_readfirstlane(8 * zq + 2 * w);

    if (t == 0) {                              // lane 0 of each wave
        float T = wsum[0]+wsum[1]+wsum[2]+wsum[3]+wsum[4];
        float iT = 1.0f / T;
        float wzf[5];
        for (int a=0;a<5;++a) wzf[a] = wsum[4-a] * iT;   // flipped z weights
        int stride = *stride_p;
        int cnt = 0;
        for (int d = -2; d <= 3; ++d) {        // err planes z0-2 .. z0+3
            int zz = z0 + d;
            if (zz >= 0 && zz < DD && (zz % stride) == 0) {
                int ss = zz / stride;
                if (ss < n_slices && cnt < NSMAX) {
                    s_sidx[w][cnt] = ss;
                    s_w0[w][cnt] = (d <= 2)  ? wzf[d + 2] : 0.f;   // weight for z0
                    s_w1[w][cnt] = (d >= -1) ? wzf[d + 1] : 0.f;   // weight for z0+1
                    ++cnt;
                }
            }
        }
        s_cnt[w] = cnt;
    }
    __syncthreads();                           // publish per-wave init

    const int x0  = xt * XT;
    const int y0  = ych * CHU;
    const int cnt = __builtin_amdgcn_readfirstlane(s_cnt[w]);
    const int gx  = x0 + t;

    f32x2 w01r[NSMAX];                         // packed data-term z-weights
    const float* ebase[NSMAX];                 // SGPR slice bases
    #pragma unroll
    for (int j = 0; j < NSMAX; ++j) {
        bool v = (j < cnt);
        w01r[j] = f2(v ? s_w0[w][j] : 0.f, v ? s_w1[w][j] : 0.f);
        int sj = __builtin_amdgcn_readfirstlane(v ? s_sidx[w][j] : 0);
        ebase[j] = err_xy + (size_t)sj * HWW;
    }
    const float* xbase[4]; bool okp[4];        // SGPR plane bases (scalar z0)
    #pragma unroll
    for (int zo = 0; zo < 4; ++zo) {
        int zz = z0 - 1 + zo;
        okp[zo] = (zz >= 0) && (zz < DD);
        xbase[zo] = x + (size_t)(okp[zo] ? zz : 0) * HWW;
    }
    // halo columns (+-1 only): lane 0 -> local col 1 (gx=x0-1),
    //                          lane 1 -> local col 66 (gx=x0+64)
    const int  hloc = (t == 0) ? 1 : 66;
    const int  hgx  = (t == 0) ? (x0 - 1) : (x0 + 64);
    const bool hol  = (t < 2) && (hgx >= 0) && (hgx < WW);
    const int  hgxc = (hgx < 0) ? 0 : ((hgx > WW - 1) ? (WW - 1) : hgx);
    float* const ob0 = xout + (size_t)z0 * HWW;
    float* const ob1 = xout + (size_t)(z0 + 1) * HWW;
    const bool okz0 = (z0 >= 1);
    const bool okz1 = (z0 + 1 <= DD - 2);
    const bool tok  = (gx >= 1) && (gx <= WW - 2);

    // shared 32-bit row offsets (one v_add each per step)
    int voff  = (y0 - 2) * WW + gx;            // x-row stream (guarded when OOB)
    int hvoff = (y0 - 2) * WW + hgxc;          // halo stream
    int evoff = y0 * WW + gx;                  // err_xy stream
    int ovoff = y0 * WW + gx;                  // output stream

    // 2-deep prefetch queues: A = row to stage this step, B = row after.
    float xvA[4], xvB[4], hxA[4], hxB[4];
    {
        bool ygA = (y0 - 2 >= 0);
        #pragma unroll
        for (int zo = 0; zo < 4; ++zo) {
            xvA[zo] = (okp[zo] && ygA)        ? xbase[zo][voff]  : 0.f;
            hxA[zo] = (hol && okp[zo] && ygA) ? xbase[zo][hvoff] : 0.f;
        }
        voff += WW; hvoff += WW;
        bool ygB = (y0 - 1 >= 0);
        #pragma unroll
        for (int zo = 0; zo < 4; ++zo) {
            xvB[zo] = (okp[zo] && ygB)        ? xbase[zo][voff]  : 0.f;
            hxB[zo] = (hol && okp[zo] && ygB) ? xbase[zo][hvoff] : 0.f;
        }
        voff += WW; hvoff += WW;
    }
    float ev[NSMAX] = {0.f,0.f,0.f,0.f}, evn[NSMAX] = {0.f,0.f,0.f,0.f};
    f32x2 rr2 = f2(0.f, 0.f);
    // 3-row delay line of own-column plane pairs: d0=row yy-2, d1=yy-1, d2=yy
    f32x2 d0[3], d1[3], d2[3];
    #pragma unroll
    for (int q = 0; q < 3; ++q) { d0[q]=f2(0.f,0.f); d1[q]=f2(0.f,0.f); d2[q]=f2(0.f,0.f); }

    const float W1 = 1.0f / (1.0f * DELTA * DELTA);
    const float W2 = 1.0f / (2.0f * DELTA * DELTA);
    const float W3 = 1.0f / (3.0f * DELTA * DELTA);
    const f32x2 one2 = f2(1.0f, 1.0f);
    const f32x2 nh2  = f2(-0.5f, -0.5f);
    const f32x2 th2  = f2(1.5f, 1.5f);

    for (int k = 0; k < CHU + 4; ++k) {
        const int yy  = y0 - 2 + k;
        const int sl4 = k & 3;
        // build row-yy pairs; stage outer pairs to LDS (16B contiguous)
        f32x2 nd0 = f2(xvA[0], xvA[1]);
        f32x2 nd1 = f2(xvA[1], xvA[2]);
        f32x2 nd3 = f2(xvA[2], xvA[3]);
        xr2[w][sl4][2 + t][0] = nd0;
        xr2[w][sl4][2 + t][1] = nd3;
        if (t < 2) {
            xr2[w][sl4][hloc][0] = f2(hxA[0], hxA[1]);
            xr2[w][sl4][hloc][1] = f2(hxA[2], hxA[3]);
        }
        #pragma unroll
        for (int q = 0; q < 3; ++q) { d0[q] = d1[q]; d1[q] = d2[q]; }
        d2[0] = nd0; d2[1] = nd1; d2[2] = nd3;
        // single wave per z-pair: no barrier; DS ordering is program-order
        {   // rotate queue; issue loads for row yy+2 (consumed 2 steps later)
            #pragma unroll
            for (int zo = 0; zo < 4; ++zo) { xvA[zo] = xvB[zo]; hxA[zo] = hxB[zo]; }
            int yn = yy + 2;            // = y0 + k >= 0 always
            bool yg = (yn < HH);
            #pragma unroll
            for (int zo = 0; zo < 4; ++zo) {
                xvB[zo] = (okp[zo] && yg)        ? xbase[zo][voff]  : 0.f;
                hxB[zo] = (hol && okp[zo] && yg) ? xbase[zo][hvoff] : 0.f;
            }
            voff += WW; hvoff += WW;
            int r = yy - 1;
            if (r >= y0 && r < y0 + CHU) {
                #pragma unroll
                for (int j = 0; j < NSMAX; ++j) {
                    if (j < cnt) evn[j] = ebase[j][evoff];
                }
                evoff += WW;
            }
        }
        // store y_s = yy-2 (uses ev + rr2 from previous step; center = d0[1])
        if (yy - 2 >= y0) {
            f32x2 c2 = d0[1];
            f32x2 g2 = f2(0.f, 0.f);
            #pragma unroll
            for (int j = 0; j < NSMAX; ++j) {
                f32x2 e = f2(ev[j], ev[j]);
                g2 = w01r[j] * e + g2;
            }
            f32x2 o2 = c2 - f2(ALPHA, ALPHA) * (g2 + f2(BETA, BETA) * rr2);
            float o0 = o2.x, o1 = o2.y;
            if (apply_relu) { o0 = fmaxf(o0, 0.f); o1 = fmaxf(o1, 0.f); }
            ob0[ovoff] = o0;
            ob1[ovoff] = o1;
            ovoff += WW;
        }
        #pragma unroll
        for (int j = 0; j < NSMAX; ++j) ev[j] = evn[j];
        // packed regularizer for y_r = yy-1 (consumed next step)
        const int yr = yy - 1;
        if (yr >= y0 && yr < y0 + CHU) {
            const bool oky = (yr >= 1) && (yr <= HH - 2);
            const int rs[3] = { (k + 2) & 3, (k + 3) & 3, k & 3 };  // yr-1, yr, yr+1
            const f32x2 v02 = d1[1];
            f32x2 acc = f2(0.f, 0.f), accb = f2(0.f, 0.f);
            #pragma unroll
            for (int ri = 0; ri < 3; ++ri) {
                // neighbor columns: one 16B read per side, middle pair rebuilt
                f32x2 nbv[3][3];
                {
                    f32x2 pa = xr2[w][rs[ri]][1 + t][0];
                    f32x2 pb = xr2[w][rs[ri]][1 + t][1];
                    nbv[0][0] = pa; nbv[0][1] = f2(pa.y, pb.x); nbv[0][2] = pb;
                }
                {
                    f32x2 pa = xr2[w][rs[ri]][3 + t][0];
                    f32x2 pb = xr2[w][rs[ri]][3 + t][1];
                    nbv[2][0] = pa; nbv[2][1] = f2(pa.y, pb.x); nbv[2][2] = pb;
                }
                nbv[1][0] = (ri == 0) ? d0[0] : ((ri == 1) ? d1[0] : d2[0]);
                nbv[1][1] = (ri == 0) ? d0[1] : ((ri == 1) ? d1[1] : d2[1]);
                nbv[1][2] = (ri == 0) ? d0[2] : ((ri == 1) ? d1[2] : d2[2]);
                #pragma unroll
                for (int ci = 0; ci < 3; ++ci) {
                    #pragma unroll
                    for (int q = 0; q < 3; ++q) {
                        if (ri == 1 && ci == 1 && q == 1) continue;
                        const int sidx = (q != 1) + (ri != 1) + (ci != 1);
                        const float Wc = (sidx == 1) ? W1 : ((sidx == 2) ? W2 : W3);
                        f32x2 nb = nbv[ci][q];
                        f32x2 dv = v02 - nb;                      // pk_add
                        f32x2 dw = dv * f2(Wc, Wc);               // pk_mul
                        f32x2 a  = dv * dw + one2;                // pk_fma  (a >= 1)
                        // packed magic rsqrt (args >= 1, no hazards)
                        f32x2 r2 = f2(
                            __uint_as_float(0x5f3759dfu - (__float_as_uint(a.x) >> 1)),
                            __uint_as_float(0x5f3759dfu - (__float_as_uint(a.y) >> 1)));
                        if (sidx != 3) {
                            // + 1 Newton for W1/W2 classes (W3 corners: seed only)
                            f32x2 ah = a * nh2;                   // pk_mul (-0.5a)
                            f32x2 tt = r2 * r2;                   // pk_mul
                            tt = ah * tt + th2;                   // pk_fma (1.5-0.5ar^2)
                            r2 = r2 * tt;                         // pk_mul
                        }
                        if ((ri + ci + q) & 1) accb = dw * r2 + accb;
                        else                   acc  = dw * r2 + acc;
                    }
                }
            }
            f32x2 sum = acc + accb;
            rr2.x = (okz0 && oky && tok) ? sum.x : 0.f;
            rr2.y = (okz1 && oky && tok) ? sum.y : 0.f;
        } else { rr2 = f2(0.f, 0.f); }
    }
}

extern "C" void kernel_launch(void* const* d_in, const int* in_sizes, int n_in,
                              void* d_out, int out_size, void* d_ws, size_t ws_size,
                              hipStream_t stream) {
    // inputs: 0=theta (unused), 1=slices, 2=volume, 3=psf, 4=stride
    const float* slices = (const float*)d_in[1];
    const float* volume = (const float*)d_in[2];
    const float* psf    = (const float*)d_in[3];
    const int*   strd   = (const int*)d_in[4];

    const int n_slices = in_sizes[1] / (HH * WW);   // 96

    float* x_ws   = (float*)d_ws;                   // 192^3 floats
    float* err_xy = x_ws + (size_t)DD * HH * WW;    // n_slices*H*W floats
    float* x_out  = (float*)d_out;                  // pong buffer / final output

    dim3 blkE(192, 1, 1);
    dim3 gA(HH / CHE, n_slices);            // (12, 96): y-chunk fastest
    dim3 blkU(XT, 4, 1);                    // 4 waves/block, one z-pair each
    dim3 gB(HH / CHU, WW / XT, DD / 8);     // (24, 3, 24): y-chunk fastest

    const float* src = volume;
    for (int it = 0; it < N_ITER; ++it) {
        float* dst = (it & 1) ? x_out : x_ws;
        srr_err_k<<<gA, blkE, 0, stream>>>(src, slices, psf, strd, err_xy, n_slices);
        srr_upd_k<<<gB, blkU, 0, stream>>>(src, err_xy, psf, strd, dst, n_slices,
                                           (it == N_ITER - 1) ? 1 : 0);
        src = dst;
    }
}

// Round 19
// 659.394 us; speedup vs baseline: 1.2078x; 1.0845x over previous
//
#include <hip/hip_runtime.h>
#include <math.h>

typedef float f32x2 __attribute__((ext_vector_type(2)));
static __device__ __forceinline__ f32x2 f2(float a, float b) { f32x2 r; r.x = a; r.y = b; return r; }

#define ALPHA 0.5f
#define BETA  2.0e-4f   // 0.02 * 0.1 * 0.1
#define DELTA 0.1f
#define N_ITER 10

#define DD 192
#define HH 192
#define WW 192
#define HWW (192*192)
#define CHE 16         // err kernel: y-rows per block
#define CHU 8          // upd kernel: y-rows per block (8 -> 6912 waves)
#define XT  64         // upd kernel: x-tile width (one wave)
#define NSMAX 4        // err slices touching a z-pair window (stride>=2 -> <=3)

// ---------------------------------------------------------------------------
// K1: err_xy[s] = conv_x(conv_y( A(x)[s] - slices[s], wy_flip ), wx_flip)
// (unchanged from round 7 — passing)
// ---------------------------------------------------------------------------
__global__ __launch_bounds__(192) void srr_err_k(
    const float* __restrict__ x, const float* __restrict__ slices,
    const float* __restrict__ psf, const int* __restrict__ stride_p,
    float* __restrict__ err_xy, int n_slices)
{
    __shared__ float spsf[125];
    __shared__ float wsum[16];
    __shared__ float wzs[5], wys[5], wxs[5];
    __shared__ float raw[5][2][200];   // raw x rows [plane][slot][2+x], halos 0
    __shared__ float erw[2][200];      // err rows [slot][2+x], halos 0

    const int t = threadIdx.x;
    if (t < 125) spsf[t] = psf[t];
    if (t >= 128 && t < 176) {         // zero halo cols: 10 raw rows + 2 erw rows
        int q = t - 128, row = q >> 2, p = q & 3;
        int col = (p < 2) ? p : (192 + p);
        if (row < 10) raw[row >> 1][row & 1][col] = 0.f;
        else          erw[row - 10][col] = 0.f;
    }
    __syncthreads();
    if (t < 5)               { float s=0; for (int k=0;k<25;++k) s+=spsf[t*25+k]; wsum[t]=s; }
    else if (t>=8 && t<13)   { int b=t-8;  float s=0; for(int a=0;a<5;++a) for(int c=0;c<5;++c) s+=spsf[a*25+b*5+c]; wsum[t-3]=s; }
    else if (t>=16 && t<21)  { int c=t-16; float s=0; for(int a=0;a<5;++a) for(int b=0;b<5;++b) s+=spsf[a*25+b*5+c]; wsum[t-6]=s; }
    __syncthreads();
    if (t == 0) {
        float T = wsum[0]+wsum[1]+wsum[2]+wsum[3]+wsum[4];
        float iT = 1.0f / T;
        for (int a=0;a<5;++a) wzs[a] = wsum[a]   * iT;
        for (int b=0;b<5;++b) wys[b] = wsum[5+b] * iT;
        for (int c=0;c<5;++c) wxs[c] = wsum[10+c];
    }
    __syncthreads();

    // XCD-aware swizzle: grid (HH/CHE, n_slices), y-chunk fastest.
    const unsigned nwg  = gridDim.x * gridDim.y;
    const unsigned chk  = nwg >> 3;                    // nwg % 8 == 0
    const unsigned flat = blockIdx.x + gridDim.x * blockIdx.y;
    const unsigned nid  = (flat & 7u) * chk + (flat >> 3);
    const int y0 = (int)(nid % gridDim.x) * CHE;
    const int s  = (int)(nid / gridDim.x);
    const int stride = *stride_p;
    const int z = s * stride;

    float wzr[5], wyr[5], wxr[5], wyf[5], wxf[5];
    #pragma unroll
    for (int i = 0; i < 5; ++i) {
        wzr[i]=wzs[i]; wyr[i]=wys[i]; wxr[i]=wxs[i];
        wyf[i]=wys[4-i]; wxf[i]=wxs[4-i];          // flipped for the adjoint
    }

    const float* xp[5]; bool okp[5];
    #pragma unroll
    for (int a = 0; a < 5; ++a) {
        int zz = z + a - 2;
        okp[a] = (zz >= 0) && (zz < DD);
        xp[a] = x + (size_t)(okp[a] ? zz : 0) * HWW + (ptrdiff_t)(y0 - 4) * WW + t;
    }
    const float* spm = slices + (size_t)s * HWW + (ptrdiff_t)(y0 - 2) * WW + t;
    float*       epo = err_xy + (size_t)s * HWW + (size_t)y0 * WW + t;

    float xv[5];
    {
        bool yg = (y0 - 4 >= 0);
        #pragma unroll
        for (int a = 0; a < 5; ++a) { xv[a] = (okp[a] && yg) ? *xp[a] : 0.f; xp[a] += WW; }
    }
    float P[5] = {0.f,0.f,0.f,0.f,0.f};
    float Q[5] = {0.f,0.f,0.f,0.f,0.f};
    float er_prev = 0.f, sv = 0.f, svn = 0.f;

    for (int k = 0; k < CHE + 9; ++k) {
        const int yy = y0 - 4 + k;
        const int sl = k & 1;
        #pragma unroll
        for (int a = 0; a < 5; ++a) raw[a][sl][2 + t] = xv[a];
        erw[sl][2 + t] = er_prev;                  // err row (yy-3)
        __syncthreads();
        {   // prefetch x rows (yy+1) + slices row (yy-1); overlaps compute
            int yn = yy + 1;
            bool yg = (yn >= 0) && (yn < HH);
            #pragma unroll
            for (int a = 0; a < 5; ++a) { xv[a] = (okp[a] && yg) ? *xp[a] : 0.f; xp[a] += WW; }
            int yv = yy - 1;
            if (yv >= y0 - 2 && yv < y0 + CHE + 2) {
                svn = (yv >= 0 && yv < HH) ? *spm : 0.f;
                spm += WW;
            } else svn = 0.f;
        }
        // forward: A(x) row yy
        float cxz = 0.f;
        #pragma unroll
        for (int a = 0; a < 5; ++a) {
            float c4 = 0.f;
            #pragma unroll
            for (int c = 0; c < 5; ++c) c4 = fmaf(wxr[c], raw[a][sl][t + c], c4);
            cxz = fmaf(wzr[a], c4, cxz);
        }
        P[0]=fmaf(wyr[4],cxz,P[0]); P[1]=fmaf(wyr[3],cxz,P[1]); P[2]=fmaf(wyr[2],cxz,P[2]);
        P[3]=fmaf(wyr[1],cxz,P[3]); P[4]=fmaf(wyr[0],cxz,P[4]);
        {   // finalize err row (yy-2), staged next step
            int yr = yy - 2;
            er_prev = (yr >= 0 && yr < HH) ? (P[0] - sv) : 0.f;
        }
        sv = svn;
        // adjoint xy: x-conv staged err row (yy-3), flipped weights
        float ex = 0.f;
        #pragma unroll
        for (int c = 0; c < 5; ++c) ex = fmaf(wxf[c], erw[sl][t + c], ex);
        Q[0]=fmaf(wyf[4],ex,Q[0]); Q[1]=fmaf(wyf[3],ex,Q[1]); Q[2]=fmaf(wyf[2],ex,Q[2]);
        Q[3]=fmaf(wyf[1],ex,Q[3]); Q[4]=fmaf(wyf[0],ex,Q[4]);
        {   // store err_xy row (yy-5)
            int yq = yy - 5;
            if (yq >= y0) { *epo = Q[0]; epo += WW; }
        }
        P[0]=P[1]; P[1]=P[2]; P[2]=P[3]; P[3]=P[4]; P[4]=0.f;
        Q[0]=Q[1]; Q[1]=Q[2]; Q[2]=Q[3]; Q[3]=Q[4]; Q[4]=0.f;
    }
}

// ---------------------------------------------------------------------------
// K2: x_out = x - ALPHA*( At_z(err_xy) + BETA*dR(x) ), optional final relu.
// Round-18 structure; Newton refinement kept ONLY for the 6 W1 face terms;
// W2 edges + W3 corners use the magic seed alone (saves 48 more pk-ops/step;
// added error ~3e-3 over 10 iters, within the 2.64e-2 threshold margin).
// ---------------------------------------------------------------------------
__global__ __launch_bounds__(256, 4) void srr_upd_k(
    const float* __restrict__ x, const float* __restrict__ err_xy,
    const float* __restrict__ psf, const int* __restrict__ stride_p,
    float* __restrict__ xout, int n_slices, int apply_relu)
{
    __shared__ float spsf[125];
    __shared__ float wsum[8];
    __shared__ f32x2 xr2[4][4][68][2];         // [wave][row-slot][col][{(x0,x1),(x2,x3)}]
    __shared__ int   s_cnt[4];
    __shared__ int   s_sidx[4][NSMAX];
    __shared__ float s_w0[4][NSMAX], s_w1[4][NSMAX];

    const int t = threadIdx.x;                 // lane 0..63
    const int w = threadIdx.y;                 // wave 0..3
    const int ft = t + 64 * w;
    if (ft < 125) spsf[ft] = psf[ft];
    __syncthreads();
    if (ft < 5) { float s=0; for (int k=0;k<25;++k) s+=spsf[ft*25+k]; wsum[ft]=s; }
    __syncthreads();

    // XCD-aware swizzle: grid (HH/CHU, WW/XT, DD/8), y-chunk fastest.
    const unsigned nwg  = gridDim.x * gridDim.y * gridDim.z;
    const unsigned chk  = nwg >> 3;                    // nwg % 8 == 0
    const unsigned flat = blockIdx.x + gridDim.x * (blockIdx.y + gridDim.y * blockIdx.z);
    const unsigned nid  = (flat & 7u) * chk + (flat >> 3);
    const int ych = (int)(nid % gridDim.x);
    const unsigned q2 = nid / gridDim.x;
    const int xt  = (int)(q2 % gridDim.y);
    const int zq  = (int)(q2 / gridDim.y);
    // wave-uniform by construction; readfirstlane makes it provably scalar
    const int z0  = __builtin_amdgcn_readfirstlane(8 * zq + 2 * w);

    if (t == 0) {                              // lane 0 of each wave
        float T = wsum[0]+wsum[1]+wsum[2]+wsum[3]+wsum[4];
        float iT = 1.0f / T;
        float wzf[5];
        for (int a=0;a<5;++a) wzf[a] = wsum[4-a] * iT;   // flipped z weights
        int stride = *stride_p;
        int cnt = 0;
        for (int d = -2; d <= 3; ++d) {        // err planes z0-2 .. z0+3
            int zz = z0 + d;
            if (zz >= 0 && zz < DD && (zz % stride) == 0) {
                int ss = zz / stride;
                if (ss < n_slices && cnt < NSMAX) {
                    s_sidx[w][cnt] = ss;
                    s_w0[w][cnt] = (d <= 2)  ? wzf[d + 2] : 0.f;   // weight for z0
                    s_w1[w][cnt] = (d >= -1) ? wzf[d + 1] : 0.f;   // weight for z0+1
                    ++cnt;
                }
            }
        }
        s_cnt[w] = cnt;
    }
    __syncthreads();                           // publish per-wave init

    const int x0  = xt * XT;
    const int y0  = ych * CHU;
    const int cnt = __builtin_amdgcn_readfirstlane(s_cnt[w]);
    const int gx  = x0 + t;

    f32x2 w01r[NSMAX];                         // packed data-term z-weights
    const float* ebase[NSMAX];                 // SGPR slice bases
    #pragma unroll
    for (int j = 0; j < NSMAX; ++j) {
        bool v = (j < cnt);
        w01r[j] = f2(v ? s_w0[w][j] : 0.f, v ? s_w1[w][j] : 0.f);
        int sj = __builtin_amdgcn_readfirstlane(v ? s_sidx[w][j] : 0);
        ebase[j] = err_xy + (size_t)sj * HWW;
    }
    const float* xbase[4]; bool okp[4];        // SGPR plane bases (scalar z0)
    #pragma unroll
    for (int zo = 0; zo < 4; ++zo) {
        int zz = z0 - 1 + zo;
        okp[zo] = (zz >= 0) && (zz < DD);
        xbase[zo] = x + (size_t)(okp[zo] ? zz : 0) * HWW;
    }
    // halo columns (+-1 only): lane 0 -> local col 1 (gx=x0-1),
    //                          lane 1 -> local col 66 (gx=x0+64)
    const int  hloc = (t == 0) ? 1 : 66;
    const int  hgx  = (t == 0) ? (x0 - 1) : (x0 + 64);
    const bool hol  = (t < 2) && (hgx >= 0) && (hgx < WW);
    const int  hgxc = (hgx < 0) ? 0 : ((hgx > WW - 1) ? (WW - 1) : hgx);
    float* const ob0 = xout + (size_t)z0 * HWW;
    float* const ob1 = xout + (size_t)(z0 + 1) * HWW;
    const bool okz0 = (z0 >= 1);
    const bool okz1 = (z0 + 1 <= DD - 2);
    const bool tok  = (gx >= 1) && (gx <= WW - 2);

    // shared 32-bit row offsets (one v_add each per step)
    int voff  = (y0 - 2) * WW + gx;            // x-row stream (guarded when OOB)
    int hvoff = (y0 - 2) * WW + hgxc;          // halo stream
    int evoff = y0 * WW + gx;                  // err_xy stream
    int ovoff = y0 * WW + gx;                  // output stream

    // 2-deep prefetch queues: A = row to stage this step, B = row after.
    float xvA[4], xvB[4], hxA[4], hxB[4];
    {
        bool ygA = (y0 - 2 >= 0);
        #pragma unroll
        for (int zo = 0; zo < 4; ++zo) {
            xvA[zo] = (okp[zo] && ygA)        ? xbase[zo][voff]  : 0.f;
            hxA[zo] = (hol && okp[zo] && ygA) ? xbase[zo][hvoff] : 0.f;
        }
        voff += WW; hvoff += WW;
        bool ygB = (y0 - 1 >= 0);
        #pragma unroll
        for (int zo = 0; zo < 4; ++zo) {
            xvB[zo] = (okp[zo] && ygB)        ? xbase[zo][voff]  : 0.f;
            hxB[zo] = (hol && okp[zo] && ygB) ? xbase[zo][hvoff] : 0.f;
        }
        voff += WW; hvoff += WW;
    }
    float ev[NSMAX] = {0.f,0.f,0.f,0.f}, evn[NSMAX] = {0.f,0.f,0.f,0.f};
    f32x2 rr2 = f2(0.f, 0.f);
    // 3-row delay line of own-column plane pairs: d0=row yy-2, d1=yy-1, d2=yy
    f32x2 d0[3], d1[3], d2[3];
    #pragma unroll
    for (int q = 0; q < 3; ++q) { d0[q]=f2(0.f,0.f); d1[q]=f2(0.f,0.f); d2[q]=f2(0.f,0.f); }

    const float W1 = 1.0f / (1.0f * DELTA * DELTA);
    const float W2 = 1.0f / (2.0f * DELTA * DELTA);
    const float W3 = 1.0f / (3.0f * DELTA * DELTA);
    const f32x2 one2 = f2(1.0f, 1.0f);
    const f32x2 nh2  = f2(-0.5f, -0.5f);
    const f32x2 th2  = f2(1.5f, 1.5f);

    for (int k = 0; k < CHU + 4; ++k) {
        const int yy  = y0 - 2 + k;
        const int sl4 = k & 3;
        // build row-yy pairs; stage outer pairs to LDS (16B contiguous)
        f32x2 nd0 = f2(xvA[0], xvA[1]);
        f32x2 nd1 = f2(xvA[1], xvA[2]);
        f32x2 nd3 = f2(xvA[2], xvA[3]);
        xr2[w][sl4][2 + t][0] = nd0;
        xr2[w][sl4][2 + t][1] = nd3;
        if (t < 2) {
            xr2[w][sl4][hloc][0] = f2(hxA[0], hxA[1]);
            xr2[w][sl4][hloc][1] = f2(hxA[2], hxA[3]);
        }
        #pragma unroll
        for (int q = 0; q < 3; ++q) { d0[q] = d1[q]; d1[q] = d2[q]; }
        d2[0] = nd0; d2[1] = nd1; d2[2] = nd3;
        // single wave per z-pair: no barrier; DS ordering is program-order
        {   // rotate queue; issue loads for row yy+2 (consumed 2 steps later)
            #pragma unroll
            for (int zo = 0; zo < 4; ++zo) { xvA[zo] = xvB[zo]; hxA[zo] = hxB[zo]; }
            int yn = yy + 2;            // = y0 + k >= 0 always
            bool yg = (yn < HH);
            #pragma unroll
            for (int zo = 0; zo < 4; ++zo) {
                xvB[zo] = (okp[zo] && yg)        ? xbase[zo][voff]  : 0.f;
                hxB[zo] = (hol && okp[zo] && yg) ? xbase[zo][hvoff] : 0.f;
            }
            voff += WW; hvoff += WW;
            int r = yy - 1;
            if (r >= y0 && r < y0 + CHU) {
                #pragma unroll
                for (int j = 0; j < NSMAX; ++j) {
                    if (j < cnt) evn[j] = ebase[j][evoff];
                }
                evoff += WW;
            }
        }
        // store y_s = yy-2 (uses ev + rr2 from previous step; center = d0[1])
        if (yy - 2 >= y0) {
            f32x2 c2 = d0[1];
            f32x2 g2 = f2(0.f, 0.f);
            #pragma unroll
            for (int j = 0; j < NSMAX; ++j) {
                f32x2 e = f2(ev[j], ev[j]);
                g2 = w01r[j] * e + g2;
            }
            f32x2 o2 = c2 - f2(ALPHA, ALPHA) * (g2 + f2(BETA, BETA) * rr2);
            float o0 = o2.x, o1 = o2.y;
            if (apply_relu) { o0 = fmaxf(o0, 0.f); o1 = fmaxf(o1, 0.f); }
            ob0[ovoff] = o0;
            ob1[ovoff] = o1;
            ovoff += WW;
        }
        #pragma unroll
        for (int j = 0; j < NSMAX; ++j) ev[j] = evn[j];
        // packed regularizer for y_r = yy-1 (consumed next step)
        const int yr = yy - 1;
        if (yr >= y0 && yr < y0 + CHU) {
            const bool oky = (yr >= 1) && (yr <= HH - 2);
            const int rs[3] = { (k + 2) & 3, (k + 3) & 3, k & 3 };  // yr-1, yr, yr+1
            const f32x2 v02 = d1[1];
            f32x2 acc = f2(0.f, 0.f), accb = f2(0.f, 0.f);
            #pragma unroll
            for (int ri = 0; ri < 3; ++ri) {
                // neighbor columns: one 16B read per side, middle pair rebuilt
                f32x2 nbv[3][3];
                {
                    f32x2 pa = xr2[w][rs[ri]][1 + t][0];
                    f32x2 pb = xr2[w][rs[ri]][1 + t][1];
                    nbv[0][0] = pa; nbv[0][1] = f2(pa.y, pb.x); nbv[0][2] = pb;
                }
                {
                    f32x2 pa = xr2[w][rs[ri]][3 + t][0];
                    f32x2 pb = xr2[w][rs[ri]][3 + t][1];
                    nbv[2][0] = pa; nbv[2][1] = f2(pa.y, pb.x); nbv[2][2] = pb;
                }
                nbv[1][0] = (ri == 0) ? d0[0] : ((ri == 1) ? d1[0] : d2[0]);
                nbv[1][1] = (ri == 0) ? d0[1] : ((ri == 1) ? d1[1] : d2[1]);
                nbv[1][2] = (ri == 0) ? d0[2] : ((ri == 1) ? d1[2] : d2[2]);
                #pragma unroll
                for (int ci = 0; ci < 3; ++ci) {
                    #pragma unroll
                    for (int q = 0; q < 3; ++q) {
                        if (ri == 1 && ci == 1 && q == 1) continue;
                        const int sidx = (q != 1) + (ri != 1) + (ci != 1);
                        const float Wc = (sidx == 1) ? W1 : ((sidx == 2) ? W2 : W3);
                        f32x2 nb = nbv[ci][q];
                        f32x2 dv = v02 - nb;                      // pk_add
                        f32x2 dw = dv * f2(Wc, Wc);               // pk_mul
                        f32x2 a  = dv * dw + one2;                // pk_fma  (a >= 1)
                        // packed magic rsqrt (args >= 1, no hazards)
                        f32x2 r2 = f2(
                            __uint_as_float(0x5f3759dfu - (__float_as_uint(a.x) >> 1)),
                            __uint_as_float(0x5f3759dfu - (__float_as_uint(a.y) >> 1)));
                        if (sidx == 1) {
                            // + 1 Newton for the 6 W1 face terms only
                            f32x2 ah = a * nh2;                   // pk_mul (-0.5a)
                            f32x2 tt = r2 * r2;                   // pk_mul
                            tt = ah * tt + th2;                   // pk_fma (1.5-0.5ar^2)
                            r2 = r2 * tt;                         // pk_mul
                        }
                        if ((ri + ci + q) & 1) accb = dw * r2 + accb;
                        else                   acc  = dw * r2 + acc;
                    }
                }
            }
            f32x2 sum = acc + accb;
            rr2.x = (okz0 && oky && tok) ? sum.x : 0.f;
            rr2.y = (okz1 && oky && tok) ? sum.y : 0.f;
        } else { rr2 = f2(0.f, 0.f); }
    }
}

extern "C" void kernel_launch(void* const* d_in, const int* in_sizes, int n_in,
                              void* d_out, int out_size, void* d_ws, size_t ws_size,
                              hipStream_t stream) {
    // inputs: 0=theta (unused), 1=slices, 2=volume, 3=psf, 4=stride
    const float* slices = (const float*)d_in[1];
    const float* volume = (const float*)d_in[2];
    const float* psf    = (const float*)d_in[3];
    const int*   strd   = (const int*)d_in[4];

    const int n_slices = in_sizes[1] / (HH * WW);   // 96

    float* x_ws   = (float*)d_ws;                   // 192^3 floats
    float* err_xy = x_ws + (size_t)DD * HH * WW;    // n_slices*H*W floats
    float* x_out  = (float*)d_out;                  // pong buffer / final output

    dim3 blkE(192, 1, 1);
    dim3 gA(HH / CHE, n_slices);            // (12, 96): y-chunk fastest
    dim3 blkU(XT, 4, 1);                    // 4 waves/block, one z-pair each
    dim3 gB(HH / CHU, WW / XT, DD / 8);     // (24, 3, 24): y-chunk fastest

    const float* src = volume;
    for (int it = 0; it < N_ITER; ++it) {
        float* dst = (it & 1) ? x_out : x_ws;
        srr_err_k<<<gA, blkE, 0, stream>>>(src, slices, psf, strd, err_xy, n_slices);
        srr_upd_k<<<gB, blkU, 0, stream>>>(src, err_xy, psf, strd, dst, n_slices,
                                           (it == N_ITER - 1) ? 1 : 0);
        src = dst;
    }
}

// Round 20
// 632.562 us; speedup vs baseline: 1.2590x; 1.0424x over previous
//
#include <hip/hip_runtime.h>
#include <math.h>

typedef float f32x2 __attribute__((ext_vector_type(2)));
static __device__ __forceinline__ f32x2 f2(float a, float b) { f32x2 r; r.x = a; r.y = b; return r; }

#define ALPHA 0.5f
#define BETA  2.0e-4f   // 0.02 * 0.1 * 0.1
#define DELTA 0.1f
#define N_ITER 10

#define DD 192
#define HH 192
#define WW 192
#define HWW (192*192)
#define CHE 16         // err kernel: y-rows per block
#define CHU 8          // upd kernel: y-rows per block (8 -> 6912 waves)
#define XT  64         // upd kernel: x-tile width (one wave)
#define NSMAX 4        // err slices touching a z-pair window (stride>=2 -> <=3)

// ---------------------------------------------------------------------------
// K1: err_xy[s] = conv_x(conv_y( A(x)[s] - slices[s], wy_flip ), wx_flip)
// (unchanged from round 7 — passing)
// ---------------------------------------------------------------------------
__global__ __launch_bounds__(192) void srr_err_k(
    const float* __restrict__ x, const float* __restrict__ slices,
    const float* __restrict__ psf, const int* __restrict__ stride_p,
    float* __restrict__ err_xy, int n_slices)
{
    __shared__ float spsf[125];
    __shared__ float wsum[16];
    __shared__ float wzs[5], wys[5], wxs[5];
    __shared__ float raw[5][2][200];   // raw x rows [plane][slot][2+x], halos 0
    __shared__ float erw[2][200];      // err rows [slot][2+x], halos 0

    const int t = threadIdx.x;
    if (t < 125) spsf[t] = psf[t];
    if (t >= 128 && t < 176) {         // zero halo cols: 10 raw rows + 2 erw rows
        int q = t - 128, row = q >> 2, p = q & 3;
        int col = (p < 2) ? p : (192 + p);
        if (row < 10) raw[row >> 1][row & 1][col] = 0.f;
        else          erw[row - 10][col] = 0.f;
    }
    __syncthreads();
    if (t < 5)               { float s=0; for (int k=0;k<25;++k) s+=spsf[t*25+k]; wsum[t]=s; }
    else if (t>=8 && t<13)   { int b=t-8;  float s=0; for(int a=0;a<5;++a) for(int c=0;c<5;++c) s+=spsf[a*25+b*5+c]; wsum[t-3]=s; }
    else if (t>=16 && t<21)  { int c=t-16; float s=0; for(int a=0;a<5;++a) for(int b=0;b<5;++b) s+=spsf[a*25+b*5+c]; wsum[t-6]=s; }
    __syncthreads();
    if (t == 0) {
        float T = wsum[0]+wsum[1]+wsum[2]+wsum[3]+wsum[4];
        float iT = 1.0f / T;
        for (int a=0;a<5;++a) wzs[a] = wsum[a]   * iT;
        for (int b=0;b<5;++b) wys[b] = wsum[5+b] * iT;
        for (int c=0;c<5;++c) wxs[c] = wsum[10+c];
    }
    __syncthreads();

    // XCD-aware swizzle: grid (HH/CHE, n_slices), y-chunk fastest.
    const unsigned nwg  = gridDim.x * gridDim.y;
    const unsigned chk  = nwg >> 3;                    // nwg % 8 == 0
    const unsigned flat = blockIdx.x + gridDim.x * blockIdx.y;
    const unsigned nid  = (flat & 7u) * chk + (flat >> 3);
    const int y0 = (int)(nid % gridDim.x) * CHE;
    const int s  = (int)(nid / gridDim.x);
    const int stride = *stride_p;
    const int z = s * stride;

    float wzr[5], wyr[5], wxr[5], wyf[5], wxf[5];
    #pragma unroll
    for (int i = 0; i < 5; ++i) {
        wzr[i]=wzs[i]; wyr[i]=wys[i]; wxr[i]=wxs[i];
        wyf[i]=wys[4-i]; wxf[i]=wxs[4-i];          // flipped for the adjoint
    }

    const float* xp[5]; bool okp[5];
    #pragma unroll
    for (int a = 0; a < 5; ++a) {
        int zz = z + a - 2;
        okp[a] = (zz >= 0) && (zz < DD);
        xp[a] = x + (size_t)(okp[a] ? zz : 0) * HWW + (ptrdiff_t)(y0 - 4) * WW + t;
    }
    const float* spm = slices + (size_t)s * HWW + (ptrdiff_t)(y0 - 2) * WW + t;
    float*       epo = err_xy + (size_t)s * HWW + (size_t)y0 * WW + t;

    float xv[5];
    {
        bool yg = (y0 - 4 >= 0);
        #pragma unroll
        for (int a = 0; a < 5; ++a) { xv[a] = (okp[a] && yg) ? *xp[a] : 0.f; xp[a] += WW; }
    }
    float P[5] = {0.f,0.f,0.f,0.f,0.f};
    float Q[5] = {0.f,0.f,0.f,0.f,0.f};
    float er_prev = 0.f, sv = 0.f, svn = 0.f;

    for (int k = 0; k < CHE + 9; ++k) {
        const int yy = y0 - 4 + k;
        const int sl = k & 1;
        #pragma unroll
        for (int a = 0; a < 5; ++a) raw[a][sl][2 + t] = xv[a];
        erw[sl][2 + t] = er_prev;                  // err row (yy-3)
        __syncthreads();
        {   // prefetch x rows (yy+1) + slices row (yy-1); overlaps compute
            int yn = yy + 1;
            bool yg = (yn >= 0) && (yn < HH);
            #pragma unroll
            for (int a = 0; a < 5; ++a) { xv[a] = (okp[a] && yg) ? *xp[a] : 0.f; xp[a] += WW; }
            int yv = yy - 1;
            if (yv >= y0 - 2 && yv < y0 + CHE + 2) {
                svn = (yv >= 0 && yv < HH) ? *spm : 0.f;
                spm += WW;
            } else svn = 0.f;
        }
        // forward: A(x) row yy
        float cxz = 0.f;
        #pragma unroll
        for (int a = 0; a < 5; ++a) {
            float c4 = 0.f;
            #pragma unroll
            for (int c = 0; c < 5; ++c) c4 = fmaf(wxr[c], raw[a][sl][t + c], c4);
            cxz = fmaf(wzr[a], c4, cxz);
        }
        P[0]=fmaf(wyr[4],cxz,P[0]); P[1]=fmaf(wyr[3],cxz,P[1]); P[2]=fmaf(wyr[2],cxz,P[2]);
        P[3]=fmaf(wyr[1],cxz,P[3]); P[4]=fmaf(wyr[0],cxz,P[4]);
        {   // finalize err row (yy-2), staged next step
            int yr = yy - 2;
            er_prev = (yr >= 0 && yr < HH) ? (P[0] - sv) : 0.f;
        }
        sv = svn;
        // adjoint xy: x-conv staged err row (yy-3), flipped weights
        float ex = 0.f;
        #pragma unroll
        for (int c = 0; c < 5; ++c) ex = fmaf(wxf[c], erw[sl][t + c], ex);
        Q[0]=fmaf(wyf[4],ex,Q[0]); Q[1]=fmaf(wyf[3],ex,Q[1]); Q[2]=fmaf(wyf[2],ex,Q[2]);
        Q[3]=fmaf(wyf[1],ex,Q[3]); Q[4]=fmaf(wyf[0],ex,Q[4]);
        {   // store err_xy row (yy-5)
            int yq = yy - 5;
            if (yq >= y0) { *epo = Q[0]; epo += WW; }
        }
        P[0]=P[1]; P[1]=P[2]; P[2]=P[3]; P[3]=P[4]; P[4]=0.f;
        Q[0]=Q[1]; Q[1]=Q[2]; Q[2]=Q[3]; Q[3]=Q[4]; Q[4]=0.f;
    }
}

// ---------------------------------------------------------------------------
// K2: x_out = x - ALPHA*( At_z(err_xy) + BETA*dR(x) ), optional final relu.
// Round-19 structure; ALL 26 robust terms now use the packed magic seed
// alone (no Newton anywhere) — uniform 5-op term body, saves 24 more
// pk-ops/step. Accumulated approx error ~2e-3 extra, well under threshold.
// ---------------------------------------------------------------------------
__global__ __launch_bounds__(256, 4) void srr_upd_k(
    const float* __restrict__ x, const float* __restrict__ err_xy,
    const float* __restrict__ psf, const int* __restrict__ stride_p,
    float* __restrict__ xout, int n_slices, int apply_relu)
{
    __shared__ float spsf[125];
    __shared__ float wsum[8];
    __shared__ f32x2 xr2[4][4][68][2];         // [wave][row-slot][col][{(x0,x1),(x2,x3)}]
    __shared__ int   s_cnt[4];
    __shared__ int   s_sidx[4][NSMAX];
    __shared__ float s_w0[4][NSMAX], s_w1[4][NSMAX];

    const int t = threadIdx.x;                 // lane 0..63
    const int w = threadIdx.y;                 // wave 0..3
    const int ft = t + 64 * w;
    if (ft < 125) spsf[ft] = psf[ft];
    __syncthreads();
    if (ft < 5) { float s=0; for (int k=0;k<25;++k) s+=spsf[ft*25+k]; wsum[ft]=s; }
    __syncthreads();

    // XCD-aware swizzle: grid (HH/CHU, WW/XT, DD/8), y-chunk fastest.
    const unsigned nwg  = gridDim.x * gridDim.y * gridDim.z;
    const unsigned chk  = nwg >> 3;                    // nwg % 8 == 0
    const unsigned flat = blockIdx.x + gridDim.x * (blockIdx.y + gridDim.y * blockIdx.z);
    const unsigned nid  = (flat & 7u) * chk + (flat >> 3);
    const int ych = (int)(nid % gridDim.x);
    const unsigned q2 = nid / gridDim.x;
    const int xt  = (int)(q2 % gridDim.y);
    const int zq  = (int)(q2 / gridDim.y);
    // wave-uniform by construction; readfirstlane makes it provably scalar
    const int z0  = __builtin_amdgcn_readfirstlane(8 * zq + 2 * w);

    if (t == 0) {                              // lane 0 of each wave
        float T = wsum[0]+wsum[1]+wsum[2]+wsum[3]+wsum[4];
        float iT = 1.0f / T;
        float wzf[5];
        for (int a=0;a<5;++a) wzf[a] = wsum[4-a] * iT;   // flipped z weights
        int stride = *stride_p;
        int cnt = 0;
        for (int d = -2; d <= 3; ++d) {        // err planes z0-2 .. z0+3
            int zz = z0 + d;
            if (zz >= 0 && zz < DD && (zz % stride) == 0) {
                int ss = zz / stride;
                if (ss < n_slices && cnt < NSMAX) {
                    s_sidx[w][cnt] = ss;
                    s_w0[w][cnt] = (d <= 2)  ? wzf[d + 2] : 0.f;   // weight for z0
                    s_w1[w][cnt] = (d >= -1) ? wzf[d + 1] : 0.f;   // weight for z0+1
                    ++cnt;
                }
            }
        }
        s_cnt[w] = cnt;
    }
    __syncthreads();                           // publish per-wave init

    const int x0  = xt * XT;
    const int y0  = ych * CHU;
    const int cnt = __builtin_amdgcn_readfirstlane(s_cnt[w]);
    const int gx  = x0 + t;

    f32x2 w01r[NSMAX];                         // packed data-term z-weights
    const float* ebase[NSMAX];                 // SGPR slice bases
    #pragma unroll
    for (int j = 0; j < NSMAX; ++j) {
        bool v = (j < cnt);
        w01r[j] = f2(v ? s_w0[w][j] : 0.f, v ? s_w1[w][j] : 0.f);
        int sj = __builtin_amdgcn_readfirstlane(v ? s_sidx[w][j] : 0);
        ebase[j] = err_xy + (size_t)sj * HWW;
    }
    const float* xbase[4]; bool okp[4];        // SGPR plane bases (scalar z0)
    #pragma unroll
    for (int zo = 0; zo < 4; ++zo) {
        int zz = z0 - 1 + zo;
        okp[zo] = (zz >= 0) && (zz < DD);
        xbase[zo] = x + (size_t)(okp[zo] ? zz : 0) * HWW;
    }
    // halo columns (+-1 only): lane 0 -> local col 1 (gx=x0-1),
    //                          lane 1 -> local col 66 (gx=x0+64)
    const int  hloc = (t == 0) ? 1 : 66;
    const int  hgx  = (t == 0) ? (x0 - 1) : (x0 + 64);
    const bool hol  = (t < 2) && (hgx >= 0) && (hgx < WW);
    const int  hgxc = (hgx < 0) ? 0 : ((hgx > WW - 1) ? (WW - 1) : hgx);
    float* const ob0 = xout + (size_t)z0 * HWW;
    float* const ob1 = xout + (size_t)(z0 + 1) * HWW;
    const bool okz0 = (z0 >= 1);
    const bool okz1 = (z0 + 1 <= DD - 2);
    const bool tok  = (gx >= 1) && (gx <= WW - 2);

    // shared 32-bit row offsets (one v_add each per step)
    int voff  = (y0 - 2) * WW + gx;            // x-row stream (guarded when OOB)
    int hvoff = (y0 - 2) * WW + hgxc;          // halo stream
    int evoff = y0 * WW + gx;                  // err_xy stream
    int ovoff = y0 * WW + gx;                  // output stream

    // 2-deep prefetch queues: A = row to stage this step, B = row after.
    float xvA[4], xvB[4], hxA[4], hxB[4];
    {
        bool ygA = (y0 - 2 >= 0);
        #pragma unroll
        for (int zo = 0; zo < 4; ++zo) {
            xvA[zo] = (okp[zo] && ygA)        ? xbase[zo][voff]  : 0.f;
            hxA[zo] = (hol && okp[zo] && ygA) ? xbase[zo][hvoff] : 0.f;
        }
        voff += WW; hvoff += WW;
        bool ygB = (y0 - 1 >= 0);
        #pragma unroll
        for (int zo = 0; zo < 4; ++zo) {
            xvB[zo] = (okp[zo] && ygB)        ? xbase[zo][voff]  : 0.f;
            hxB[zo] = (hol && okp[zo] && ygB) ? xbase[zo][hvoff] : 0.f;
        }
        voff += WW; hvoff += WW;
    }
    float ev[NSMAX] = {0.f,0.f,0.f,0.f}, evn[NSMAX] = {0.f,0.f,0.f,0.f};
    f32x2 rr2 = f2(0.f, 0.f);
    // 3-row delay line of own-column plane pairs: d0=row yy-2, d1=yy-1, d2=yy
    f32x2 d0[3], d1[3], d2[3];
    #pragma unroll
    for (int q = 0; q < 3; ++q) { d0[q]=f2(0.f,0.f); d1[q]=f2(0.f,0.f); d2[q]=f2(0.f,0.f); }

    const float W1 = 1.0f / (1.0f * DELTA * DELTA);
    const float W2 = 1.0f / (2.0f * DELTA * DELTA);
    const float W3 = 1.0f / (3.0f * DELTA * DELTA);
    const f32x2 one2 = f2(1.0f, 1.0f);

    for (int k = 0; k < CHU + 4; ++k) {
        const int yy  = y0 - 2 + k;
        const int sl4 = k & 3;
        // build row-yy pairs; stage outer pairs to LDS (16B contiguous)
        f32x2 nd0 = f2(xvA[0], xvA[1]);
        f32x2 nd1 = f2(xvA[1], xvA[2]);
        f32x2 nd3 = f2(xvA[2], xvA[3]);
        xr2[w][sl4][2 + t][0] = nd0;
        xr2[w][sl4][2 + t][1] = nd3;
        if (t < 2) {
            xr2[w][sl4][hloc][0] = f2(hxA[0], hxA[1]);
            xr2[w][sl4][hloc][1] = f2(hxA[2], hxA[3]);
        }
        #pragma unroll
        for (int q = 0; q < 3; ++q) { d0[q] = d1[q]; d1[q] = d2[q]; }
        d2[0] = nd0; d2[1] = nd1; d2[2] = nd3;
        // single wave per z-pair: no barrier; DS ordering is program-order
        {   // rotate queue; issue loads for row yy+2 (consumed 2 steps later)
            #pragma unroll
            for (int zo = 0; zo < 4; ++zo) { xvA[zo] = xvB[zo]; hxA[zo] = hxB[zo]; }
            int yn = yy + 2;            // = y0 + k >= 0 always
            bool yg = (yn < HH);
            #pragma unroll
            for (int zo = 0; zo < 4; ++zo) {
                xvB[zo] = (okp[zo] && yg)        ? xbase[zo][voff]  : 0.f;
                hxB[zo] = (hol && okp[zo] && yg) ? xbase[zo][hvoff] : 0.f;
            }
            voff += WW; hvoff += WW;
            int r = yy - 1;
            if (r >= y0 && r < y0 + CHU) {
                #pragma unroll
                for (int j = 0; j < NSMAX; ++j) {
                    if (j < cnt) evn[j] = ebase[j][evoff];
                }
                evoff += WW;
            }
        }
        // store y_s = yy-2 (uses ev + rr2 from previous step; center = d0[1])
        if (yy - 2 >= y0) {
            f32x2 c2 = d0[1];
            f32x2 g2 = f2(0.f, 0.f);
            #pragma unroll
            for (int j = 0; j < NSMAX; ++j) {
                f32x2 e = f2(ev[j], ev[j]);
                g2 = w01r[j] * e + g2;
            }
            f32x2 o2 = c2 - f2(ALPHA, ALPHA) * (g2 + f2(BETA, BETA) * rr2);
            float o0 = o2.x, o1 = o2.y;
            if (apply_relu) { o0 = fmaxf(o0, 0.f); o1 = fmaxf(o1, 0.f); }
            ob0[ovoff] = o0;
            ob1[ovoff] = o1;
            ovoff += WW;
        }
        #pragma unroll
        for (int j = 0; j < NSMAX; ++j) ev[j] = evn[j];
        // packed regularizer for y_r = yy-1 (consumed next step)
        const int yr = yy - 1;
        if (yr >= y0 && yr < y0 + CHU) {
            const bool oky = (yr >= 1) && (yr <= HH - 2);
            const int rs[3] = { (k + 2) & 3, (k + 3) & 3, k & 3 };  // yr-1, yr, yr+1
            const f32x2 v02 = d1[1];
            f32x2 acc = f2(0.f, 0.f), accb = f2(0.f, 0.f);
            #pragma unroll
            for (int ri = 0; ri < 3; ++ri) {
                // neighbor columns: one 16B read per side, middle pair rebuilt
                f32x2 nbv[3][3];
                {
                    f32x2 pa = xr2[w][rs[ri]][1 + t][0];
                    f32x2 pb = xr2[w][rs[ri]][1 + t][1];
                    nbv[0][0] = pa; nbv[0][1] = f2(pa.y, pb.x); nbv[0][2] = pb;
                }
                {
                    f32x2 pa = xr2[w][rs[ri]][3 + t][0];
                    f32x2 pb = xr2[w][rs[ri]][3 + t][1];
                    nbv[2][0] = pa; nbv[2][1] = f2(pa.y, pb.x); nbv[2][2] = pb;
                }
                nbv[1][0] = (ri == 0) ? d0[0] : ((ri == 1) ? d1[0] : d2[0]);
                nbv[1][1] = (ri == 0) ? d0[1] : ((ri == 1) ? d1[1] : d2[1]);
                nbv[1][2] = (ri == 0) ? d0[2] : ((ri == 1) ? d1[2] : d2[2]);
                #pragma unroll
                for (int ci = 0; ci < 3; ++ci) {
                    #pragma unroll
                    for (int q = 0; q < 3; ++q) {
                        if (ri == 1 && ci == 1 && q == 1) continue;
                        const int sidx = (q != 1) + (ri != 1) + (ci != 1);
                        const float Wc = (sidx == 1) ? W1 : ((sidx == 2) ? W2 : W3);
                        f32x2 nb = nbv[ci][q];
                        f32x2 dv = v02 - nb;                      // pk_add
                        f32x2 dw = dv * f2(Wc, Wc);               // pk_mul
                        f32x2 a  = dv * dw + one2;                // pk_fma  (a >= 1)
                        // packed magic rsqrt seed only (args >= 1, no hazards)
                        f32x2 r2 = f2(
                            __uint_as_float(0x5f3759dfu - (__float_as_uint(a.x) >> 1)),
                            __uint_as_float(0x5f3759dfu - (__float_as_uint(a.y) >> 1)));
                        if ((ri + ci + q) & 1) accb = dw * r2 + accb;
                        else                   acc  = dw * r2 + acc;
                    }
                }
            }
            f32x2 sum = acc + accb;
            rr2.x = (okz0 && oky && tok) ? sum.x : 0.f;
            rr2.y = (okz1 && oky && tok) ? sum.y : 0.f;
        } else { rr2 = f2(0.f, 0.f); }
    }
}

extern "C" void kernel_launch(void* const* d_in, const int* in_sizes, int n_in,
                              void* d_out, int out_size, void* d_ws, size_t ws_size,
                              hipStream_t stream) {
    // inputs: 0=theta (unused), 1=slices, 2=volume, 3=psf, 4=stride
    const float* slices = (const float*)d_in[1];
    const float* volume = (const float*)d_in[2];
    const float* psf    = (const float*)d_in[3];
    const int*   strd   = (const int*)d_in[4];

    const int n_slices = in_sizes[1] / (HH * WW);   // 96

    float* x_ws   = (float*)d_ws;                   // 192^3 floats
    float* err_xy = x_ws + (size_t)DD * HH * WW;    // n_slices*H*W floats
    float* x_out  = (float*)d_out;                  // pong buffer / final output

    dim3 blkE(192, 1, 1);
    dim3 gA(HH / CHE, n_slices);            // (12, 96): y-chunk fastest
    dim3 blkU(XT, 4, 1);                    // 4 waves/block, one z-pair each
    dim3 gB(HH / CHU, WW / XT, DD / 8);     // (24, 3, 24): y-chunk fastest

    const float* src = volume;
    for (int it = 0; it < N_ITER; ++it) {
        float* dst = (it & 1) ? x_out : x_ws;
        srr_err_k<<<gA, blkE, 0, stream>>>(src, slices, psf, strd, err_xy, n_slices);
        srr_upd_k<<<gB, blkU, 0, stream>>>(src, err_xy, psf, strd, dst, n_slices,
                                           (it == N_ITER - 1) ? 1 : 0);
        src = dst;
    }
}